// Round 9
// baseline (48.763 us; speedup 1.0000x reference)
//
#include <hip/hip_runtime.h>

// Fused two-sided GraphSage-style embed + linear + dot. Single kernel.
// B=16384, MAX_DEG=50, D=64. Block = 256 threads (4 waves), EPB=8 elems,
// grid = 2048. LDS ~19.5 KB/block -> up to 8 blocks/CU.
// Phase 0: in-kernel mask-layout detection (wave 0, ballots).
// Phase 1: lane = embedding dim. Metadata for both elems -> SoA compaction
//          (byte-offset, w) into LDS -> interleaved scalar-row gathers over
//          all 4 (elem,side) streams with READFIRSTLANE scalar-base
//          addressing (row base in SGPRs, SALU address math, 1 VALU/row).
// Phase 2: mat-vec mini-GEMM, wave = (side, 4 elems), W amortized, unroll 2.
// Phase 3: select + dot + wave reduce.

constexpr int KDEG  = 50;
constexpr int DIM   = 64;
constexpr int SLOTS = 56;             // KDEG padded to multiple of 8
constexpr int EPB   = 8;              // elements per block

template <typename MT>
__device__ __forceinline__ void load_meta(const void* __restrict__ mask_p,
                                          const float* __restrict__ sel,
                                          const int* __restrict__ neibs,
                                          int base, int lane,
                                          int& idx, float& w, bool& act) {
  if (lane < KDEG) {
    MT m    = ((const MT*)mask_p)[base + lane];
    float s = sel[base + lane];
    idx     = neibs[base + lane];
    act     = (m != (MT)0);
    w       = act ? s : 0.0f;
  } else { idx = 0; w = 0.0f; act = false; }
}

// Compact active (byte_off, w) into slots [0,cnt); fill tail with zeros. SoA.
__device__ __forceinline__ int compact_side(int lane, int idx, float w, bool act,
                                            int* __restrict__ soff,
                                            float* __restrict__ sw) {
  unsigned long long balA = __ballot(act);
  unsigned long long balI = __ballot(!act && (lane < SLOTS));
  int cnt = __popcll(balA);
  unsigned long long below = (1ULL << lane) - 1ULL;
  int pos = act ? __popcll(balA & below)
                : cnt + __popcll(balI & below);
  if (lane < SLOTS) {
    soff[pos] = act ? (idx << 8) : 0;   // byte offset: idx * DIM * 4 = idx*256
    sw[pos]   = act ? w : 0.0f;
  }
  return cnt;
}

__global__ __launch_bounds__(256) void fused_graphsage_dot(
    const int* __restrict__ nodes_u, const int* __restrict__ nodes_v,
    const int* __restrict__ u_neibs, const int* __restrict__ v_neibs,
    const void* __restrict__ u_mask_p, const void* __restrict__ v_mask_p,
    const float* __restrict__ u_sel, const float* __restrict__ v_sel,
    const float* __restrict__ u2e, const float* __restrict__ v2e,
    const float* __restrict__ Wu, const float* __restrict__ bu,
    const float* __restrict__ Wv, const float* __restrict__ bv,
    float* __restrict__ out)
{
  __shared__ float sx  [EPB][256];      // [self_u|agg_u|self_v|agg_v] per elem
  __shared__ float slin[2][EPB][DIM];   // mat-vec results per side
  __shared__ int   soff[EPB][2][SLOTS];
  __shared__ float swt [EPB][2][SLOTS];
  __shared__ int   slay;

  const int lane = threadIdx.x & 63;    // = embedding dim in phase 1
  const int wvid = threadIdx.x >> 6;    // 0..3
  const int eb0  = blockIdx.x * EPB;
  const int e0   = wvid * 2, e1 = e0 + 1;
  const int g0   = eb0 + e0, g1 = eb0 + e1;
  const int b0   = g0 * KDEG, b1 = g1 * KDEG;

  // self-embedding loads issued first (independent of everything below)
  float self_u0 = u2e[(size_t)nodes_u[g0] * DIM + lane];
  float self_v0 = v2e[(size_t)nodes_v[g0] * DIM + lane];
  float self_u1 = u2e[(size_t)nodes_u[g1] * DIM + lane];
  float self_v1 = v2e[(size_t)nodes_v[g1] * DIM + lane];

  // ---- Phase 0: mask storage layout detection (bool dtype ambiguity) ------
  // lay 0: int32 0/1   lay 1: uint8 0/1   lay 2: float32 0.0/1.0
  if (wvid == 0) {
    uchar4 b4 = ((const uchar4*)u_mask_p)[lane];   // first 256 bytes
    bool gt1  = (b4.x > 1) | (b4.y > 1) | (b4.z > 1) | (b4.w > 1);
    bool offw = ((b4.y | b4.z | b4.w) != 0);
    unsigned long long bg = __ballot(gt1);
    unsigned long long bo = __ballot(offw);
    if (lane == 0) slay = bg ? 2 : (bo ? 1 : 0);
  }
  __syncthreads();
  const int lay = slay;

  // ---- Phase 1a: metadata for BOTH elements, then SoA compaction -----------
  int iu0, iv0, iu1, iv1; float wu0, wv0, wu1, wv1; bool au0_, av0_, au1_, av1_;
  if (lay == 0) {
    load_meta<int>(u_mask_p, u_sel, u_neibs, b0, lane, iu0, wu0, au0_);
    load_meta<int>(v_mask_p, v_sel, v_neibs, b0, lane, iv0, wv0, av0_);
    load_meta<int>(u_mask_p, u_sel, u_neibs, b1, lane, iu1, wu1, au1_);
    load_meta<int>(v_mask_p, v_sel, v_neibs, b1, lane, iv1, wv1, av1_);
  } else if (lay == 1) {
    load_meta<unsigned char>(u_mask_p, u_sel, u_neibs, b0, lane, iu0, wu0, au0_);
    load_meta<unsigned char>(v_mask_p, v_sel, v_neibs, b0, lane, iv0, wv0, av0_);
    load_meta<unsigned char>(u_mask_p, u_sel, u_neibs, b1, lane, iu1, wu1, au1_);
    load_meta<unsigned char>(v_mask_p, v_sel, v_neibs, b1, lane, iv1, wv1, av1_);
  } else {
    load_meta<float>(u_mask_p, u_sel, u_neibs, b0, lane, iu0, wu0, au0_);
    load_meta<float>(v_mask_p, v_sel, v_neibs, b0, lane, iv0, wv0, av0_);
    load_meta<float>(u_mask_p, u_sel, u_neibs, b1, lane, iu1, wu1, au1_);
    load_meta<float>(v_mask_p, v_sel, v_neibs, b1, lane, iv1, wv1, av1_);
  }
  const int cnt_u0 = compact_side(lane, iu0, wu0, au0_, soff[e0][0], swt[e0][0]);
  const int cnt_v0 = compact_side(lane, iv0, wv0, av0_, soff[e0][1], swt[e0][1]);
  const int cnt_u1 = compact_side(lane, iu1, wu1, au1_, soff[e1][0], swt[e1][0]);
  const int cnt_v1 = compact_side(lane, iv1, wv1, av1_, soff[e1][1], swt[e1][1]);

  // ---- Phase 1b: scalar-base gathers (4 streams, SGPR row base) ------------
  float accu0 = 0.f, accv0 = 0.f, accu1 = 0.f, accv1 = 0.f;
  {
    const int*   __restrict__ pO0 = soff[e0][0];
    const float* __restrict__ pW0 = swt [e0][0];
    const int*   __restrict__ pO1 = soff[e0][1];
    const float* __restrict__ pW1 = swt [e0][1];
    const int*   __restrict__ pO2 = soff[e1][0];
    const float* __restrict__ pW2 = swt [e1][0];
    const int*   __restrict__ pO3 = soff[e1][1];
    const float* __restrict__ pW3 = swt [e1][1];
    const char*  __restrict__ ub  = (const char*)u2e;
    const char*  __restrict__ vb  = (const char*)v2e;

    int cmax = max(max(cnt_u0, cnt_v0), max(cnt_u1, cnt_v1));
    int cm4  = (cmax + 3) & ~3;         // tail slots hold (0, 0.0f)
    for (int s = 0; s < cm4; s += 4) {
      #pragma unroll
      for (int j = 0; j < 4; ++j) {
        const int t = s + j;
        // row bases are wave-uniform (LDS broadcast) -> force into SGPRs
        int o0 = __builtin_amdgcn_readfirstlane(pO0[t]);
        int o1 = __builtin_amdgcn_readfirstlane(pO1[t]);
        int o2 = __builtin_amdgcn_readfirstlane(pO2[t]);
        int o3 = __builtin_amdgcn_readfirstlane(pO3[t]);
        float r0 = ((const float*)(ub + o0))[lane];
        float r1 = ((const float*)(vb + o1))[lane];
        float r2 = ((const float*)(ub + o2))[lane];
        float r3 = ((const float*)(vb + o3))[lane];
        accu0 = fmaf(pW0[t], r0, accu0);
        accv0 = fmaf(pW1[t], r1, accv0);
        accu1 = fmaf(pW2[t], r2, accu1);
        accv1 = fmaf(pW3[t], r3, accv1);
      }
    }
  }

  // ---- stage concat vectors (all 64 lanes, no cross-lane reduce needed) ----
  sx[e0][lane]       = self_u0;
  sx[e0][ 64 + lane] = accu0 * (1.0f / fmaxf((float)cnt_u0, 1.0f));
  sx[e0][128 + lane] = self_v0;
  sx[e0][192 + lane] = accv0 * (1.0f / fmaxf((float)cnt_v0, 1.0f));
  sx[e1][lane]       = self_u1;
  sx[e1][ 64 + lane] = accu1 * (1.0f / fmaxf((float)cnt_u1, 1.0f));
  sx[e1][128 + lane] = self_v1;
  sx[e1][192 + lane] = accv1 * (1.0f / fmaxf((float)cnt_v1, 1.0f));
  __syncthreads();

  // ---- Phase 2: mat-vec mini-GEMM ------------------------------------------
  // wave = (side, 4 elements), lane = output dim, k = 0..127
  {
    const int side = wvid & 1;
    const int eb   = (wvid >> 1) * 4;
    const float* __restrict__ W = side ? Wv : Wu;
    const float  bias = side ? bv[lane] : bu[lane];
    float a0 = bias, a1 = bias, a2 = bias, a3 = bias;
    const int xoff = side * 128;

    #pragma unroll 2
    for (int k4 = 0; k4 < 32; ++k4) {
      const int k = k4 * 4;
      float w0 = W[(k + 0) * DIM + lane];
      float w1 = W[(k + 1) * DIM + lane];
      float w2 = W[(k + 2) * DIM + lane];
      float w3 = W[(k + 3) * DIM + lane];
      float4 x0 = *(const float4*)&sx[eb + 0][xoff + k];
      float4 x1 = *(const float4*)&sx[eb + 1][xoff + k];
      float4 x2 = *(const float4*)&sx[eb + 2][xoff + k];
      float4 x3 = *(const float4*)&sx[eb + 3][xoff + k];
      a0 = fmaf(x0.x, w0, a0); a0 = fmaf(x0.y, w1, a0);
      a0 = fmaf(x0.z, w2, a0); a0 = fmaf(x0.w, w3, a0);
      a1 = fmaf(x1.x, w0, a1); a1 = fmaf(x1.y, w1, a1);
      a1 = fmaf(x1.z, w2, a1); a1 = fmaf(x1.w, w3, a1);
      a2 = fmaf(x2.x, w0, a2); a2 = fmaf(x2.y, w1, a2);
      a2 = fmaf(x2.z, w2, a2); a2 = fmaf(x2.w, w3, a2);
      a3 = fmaf(x3.x, w0, a3); a3 = fmaf(x3.y, w1, a3);
      a3 = fmaf(x3.z, w2, a3); a3 = fmaf(x3.w, w3, a3);
    }
    slin[side][eb + 0][lane] = a0;
    slin[side][eb + 1][lane] = a1;
    slin[side][eb + 2][lane] = a2;
    slin[side][eb + 3][lane] = a3;
  }
  __syncthreads();

  // ---- Phase 3: select + dot (counts still in registers) -------------------
  {
    float ue = (cnt_u0 > 0) ? slin[0][e0][lane] : sx[e0][lane];
    float ve = (cnt_v0 > 0) ? slin[1][e0][lane] : sx[e0][128 + lane];
    float p = ue * ve;
    #pragma unroll
    for (int off = 32; off > 0; off >>= 1) p += __shfl_xor(p, off, 64);
    if (lane == 0) out[g0] = p;
  }
  {
    float ue = (cnt_u1 > 0) ? slin[0][e1][lane] : sx[e1][lane];
    float ve = (cnt_v1 > 0) ? slin[1][e1][lane] : sx[e1][128 + lane];
    float p = ue * ve;
    #pragma unroll
    for (int off = 32; off > 0; off >>= 1) p += __shfl_xor(p, off, 64);
    if (lane == 0) out[g1] = p;
  }
}

extern "C" void kernel_launch(void* const* d_in, const int* in_sizes, int n_in,
                              void* d_out, int out_size, void* d_ws, size_t ws_size,
                              hipStream_t stream) {
  const int*   nodes_u = (const int*)  d_in[0];
  const int*   nodes_v = (const int*)  d_in[1];
  const int*   u_neibs = (const int*)  d_in[2];
  const int*   v_neibs = (const int*)  d_in[3];
  const void*  u_mask  =               d_in[4];
  const void*  v_mask  =               d_in[5];
  const float* u_sel   = (const float*)d_in[6];
  const float* v_sel   = (const float*)d_in[7];
  const float* u2e     = (const float*)d_in[8];
  const float* v2e     = (const float*)d_in[9];
  const float* Wu      = (const float*)d_in[10];
  const float* bu      = (const float*)d_in[11];
  const float* Wv      = (const float*)d_in[12];
  const float* bv      = (const float*)d_in[13];
  float* out = (float*)d_out;

  const int batch = in_sizes[0];           // 16384
  fused_graphsage_dot<<<batch / EPB, 256, 0, stream>>>(
      nodes_u, nodes_v, u_neibs, v_neibs, u_mask, v_mask, u_sel, v_sel,
      u2e, v2e, Wu, bu, Wv, bv, out);
}